// Round 9
// baseline (105.299 us; speedup 1.0000x reference)
//
#include <hip/hip_runtime.h>
#include <stdint.h>

// Bilateral filter denoiser: K=5, sigma_s=2.0, sigma_r=0.1, B=8,C=3,H=512,W=512, fp32.
// weight(dy,dx) = exp(-(n-c)^2/(2*0.1^2)) * exp(-(dx^2+dy^2)/8)
//              = exp2( RC*(n-c)^2 + L[r2] ),  r2 = (dy-2)^2+(dx-2)^2, L[r2] = -r2*log2(e)/8
// arg computed as fma(fma(RC,n,B), n, C0L); C-sets chained just-in-time (row order
// 2,1,3,0,4) so peak C-live is 4 sets.
//
// ROUND 9: software exp2 v2 -- ROBUST primitives only. Round 8's magic-number version
// ((t+1.5*2^23)-magic round-trip + mod-512 exponent wrap) was miscompiled under the
// harness's fast-math flags (outputs outside the input convex hull => corrupt bit math,
// not mere precision). v2 uses only non-foldable ops:
//   r = rintf(t)            (v_rndne_f32 -- intrinsic, not an algebraic identity)
//   f = t - r in [-1/2,1/2] (true subtraction)
//   p = deg-3 Taylor 2^f    (3 v_pk_fma_f32; rel err <= 8.5e-4, threshold is 2e-2)
//   w = ldexp(p, (int)r)    (v_ldexp_f32: exact p*2^i, no bit tricks; i in [-74,0])
// 10 full-rate VALU instrs per 2 exps (~20 issue cyc) vs 2 trans v_exp_f32 (~32 cyc by
// the round-0 VALUBusy fit: 192 exps were 78% of the wave issue budget).
//
// 8 px/thread (four float2 halves -> v_pk_* packed fp32), 64x32 tile, 256 threads.
// ALL compute is MACROS: the inliner OUTLINES large [&]-capture lambdas at 24 call
// sites (capture struct in scratch, +200 MB HBM traffic -- rounds 3-4).
// Single-tile structure (r7 tile-pair pipeline was neutral-negative).
//
// Staging: async global->LDS via __builtin_amdgcn_global_load_lds width=16.
// Tile rows are 72 words (288B = 18x16B units) covering gx in [tileX0-4, tileX0+68):
//   - rows 16B-aligned, LDS written linearly (wave-uniform base + lane*16) as HW needs
//   - per-lane global address handles y-reflect; x CLAMPED to [0,508] (garbage cols are
//     outside the compute window except 2 cols on x-border blocks, fixed up scalar)
//   - 648 units = 3 gload_lds instrs/wave (64 + 64 + 34 active lanes)
// Compute window per thread = 16 words [txg*8, txg*8+16): four aligned ds_read_b128;
// pixels are words +4..+11 (Q1,Q2), taps use words +2..+13.
// Center tap: weight == 1 exactly -> ws init 1, acc init c; ws>=1 so no clip, rcp ok.

#define KK 5
#define HALO 2
#define TX 64          // tile width (pixels)
#define TY 32          // tile height
#define PXT 8          // pixels per thread along x
#define LW 72          // staged words per row: [tileX0-4, tileX0+68)
#define LH (TY + 2*HALO)   // 36 rows
#define LSTRIDE 72         // 288B rows, 16B-aligned
#define UNITS_PER_ROW 18   // 72 words / 4
#define IMG_H 512
#define IMG_W 512

typedef float v2f __attribute__((ext_vector_type(2)));
typedef float v4f __attribute__((ext_vector_type(4)));

#if defined(__has_builtin)
#if __has_builtin(__builtin_amdgcn_rcpf)
#define FAST_RCP(x) __builtin_amdgcn_rcpf(x)
#else
#define FAST_RCP(x) (1.0f / (x))
#endif
#if __has_builtin(__builtin_amdgcn_ldexpf)
#define LDEXPF(p, i) __builtin_amdgcn_ldexpf((p), (i))
#else
// i in [-74,0] -> biased exp in [53,127]: plain exponent build, no wrap cases.
#define LDEXPF(p, i) ((p) * __builtin_bit_cast(float, (uint32_t)(((i) + 127) << 23)))
#endif
#if __has_builtin(__builtin_amdgcn_global_load_lds)
#define HAVE_GLOAD_LDS 1
#endif
#else
#define FAST_RCP(x) (1.0f / (x))
#define LDEXPF(p, i) ldexpf((p), (i))
#endif

__device__ __forceinline__ int reflect_idx(int i, int n) {
    i = (i < 0) ? -i : i;
    i = (i >= n) ? (2 * n - 2 - i) : i;
    return i;
}

#ifdef HAVE_GLOAD_LDS
__device__ __forceinline__ void async_copy16(const float* g, float* l) {
    // generic->AS(1) cast for global src; LDS ptr via 32-bit truncation (flat LDS
    // addresses are aperture|offset with 4GB-aligned aperture -> low 32 bits = offset).
    auto gp = (const __attribute__((address_space(1))) void*)g;
    auto lp = (__attribute__((address_space(3))) void*)(uint32_t)(uintptr_t)l;
    __builtin_amdgcn_global_load_lds(gp, lp, 16, 0, 0);
}
#endif

// ---- macro compute core (no function boundaries) ----
#define PKFMA(a, b, c) __builtin_elementwise_fma((a), (b), (c))

// software exp2 on v2f, t in [-74, 0]:
//   r = rintf(t); f = t - r in [-0.5, 0.5]; p = 1 + f*(c1 + f*(c2 + f*c3));
//   dst = ldexp(p, (int)r). All ops non-foldable; no rounding-mode or bit-wrap tricks.
#define EXP2V(dst, t) {                                                         \
    float rx_ = __builtin_rintf((t).x);                                         \
    float ry_ = __builtin_rintf((t).y);                                         \
    v2f rv_ = {rx_, ry_};                                                       \
    v2f f_ = (t) - rv_;                                                         \
    v2f p_ = PKFMA(PKFMA(PKFMA(XC3v, f_, XC2v), f_, XC1v), f_, ONEv);           \
    (dst).x = LDEXPF(p_.x, (int)rx_);                                           \
    (dst).y = LDEXPF(p_.y, (int)ry_);                                           \
}

#define TAP(nA, nB, nC, nD, CA, CB, CC, CD) {                                   \
    v2f tA_ = PKFMA(PKFMA(RCv, (nA), BA), (nA), (CA));                          \
    v2f tB_ = PKFMA(PKFMA(RCv, (nB), BB), (nB), (CB));                          \
    v2f tC_ = PKFMA(PKFMA(RCv, (nC), BC), (nC), (CC));                          \
    v2f tD_ = PKFMA(PKFMA(RCv, (nD), BD), (nD), (CD));                          \
    v2f eA_, eB_, eC_, eD_;                                                     \
    EXP2V(eA_, tA_);                                                            \
    EXP2V(eB_, tB_);                                                            \
    EXP2V(eC_, tC_);                                                            \
    EXP2V(eD_, tD_);                                                            \
    wsA += eA_; wsB += eB_; wsC += eC_; wsD += eD_;                             \
    accA = PKFMA(eA_, (nA), accA);                                              \
    accB = PKFMA(eB_, (nB), accB);                                              \
    accC = PKFMA(eC_, (nC), accC);                                              \
    accD = PKFMA(eD_, (nD), accD);                                              \
}

// window words w0..w15 (quads Qa..Qd), taps use w2..w13.
// even pairs Ek=(w2k,w2k+1) k=1..6; odd pairs Ok=(w2k+1,w2k+2) k=1..5.
//  dx0:(E1..E4)  dx1:(O1..O4)  dx2:(E2..E5)  dx3:(O2..O5)  dx4:(E3..E6)
#define DOROW(Qa, Qb, Qc, Qd, CaA,CaB,CaC,CaD, CbA,CbB,CbC,CbD, CcA,CcB,CcC,CcD, CENTER) { \
    v2f E1_ = {Qa[2], Qa[3]};                                                   \
    v2f E2_ = {Qb[0], Qb[1]};                                                   \
    v2f E3_ = {Qb[2], Qb[3]};                                                   \
    v2f E4_ = {Qc[0], Qc[1]};                                                   \
    v2f E5_ = {Qc[2], Qc[3]};                                                   \
    v2f E6_ = {Qd[0], Qd[1]};                                                   \
    v2f O1_ = {Qa[3], Qb[0]};                                                   \
    v2f O2_ = {Qb[1], Qb[2]};                                                   \
    v2f O3_ = {Qb[3], Qc[0]};                                                   \
    v2f O4_ = {Qc[1], Qc[2]};                                                   \
    v2f O5_ = {Qc[3], Qd[0]};                                                   \
    TAP(E1_, E2_, E3_, E4_, CaA, CaB, CaC, CaD);          /* dx = 0 */          \
    TAP(O1_, O2_, O3_, O4_, CbA, CbB, CbC, CbD);          /* dx = 1 */          \
    if (!(CENTER)) TAP(E2_, E3_, E4_, E5_, CcA, CcB, CcC, CcD); /* dx = 2 */    \
    TAP(O2_, O3_, O4_, O5_, CbA, CbB, CbC, CbD);          /* dx = 3 */          \
    TAP(E3_, E4_, E5_, E6_, CaA, CaB, CaC, CaD);          /* dx = 4 */          \
}

#define LDROW(dy, Qa, Qb, Qc, Qd) {                                             \
    const v4f* p_ = reinterpret_cast<const v4f*>(&tile[(ty + (dy)) * LSTRIDE + lxw]); \
    Qa = p_[0]; Qb = p_[1]; Qc = p_[2]; Qd = p_[3];                             \
}

__global__ __launch_bounds__(256, 4)
void bilateral_kernel(const float* __restrict__ x, float* __restrict__ out) {
    __shared__ alignas(16) float tile[LH * LSTRIDE];

    const int tid = threadIdx.x;
    const int tileX0 = blockIdx.x * TX;
    const int tileY0 = blockIdx.y * TY;
    const int img = blockIdx.z;
    const float* __restrict__ src = x + (size_t)img * (IMG_H * IMG_W);
    float* __restrict__ dst = out + (size_t)img * (IMG_H * IMG_W);

#ifdef HAVE_GLOAD_LDS
    // ---- async stage: 648 16B units over 4 waves (162 each = 64 + 64 + 34) ----
    {
        const int wv = tid >> 6;
        const int ln = tid & 63;
        const int u0 = wv * 162;
        #pragma unroll
        for (int k = 0; k < 3; k++) {
            if (k < 2 || ln < 34) {
                int u = u0 + k * 64 + ln;
                int r = u / UNITS_PER_ROW;
                int c = u - r * UNITS_PER_ROW;
                int gy = reflect_idx(tileY0 - HALO + r, IMG_H);
                int gxw = tileX0 - 4 + c * 4;
                gxw = max(gxw, 0); gxw = min(gxw, IMG_W - 4);
                async_copy16(src + gy * IMG_W + gxw, &tile[(u0 + k * 64) * 4]);
            }
        }
    }
    __syncthreads();   // drains vmcnt -> gload_lds data visible

    // ---- x-border fixup: clamped loads put wrong values in 2 needed halo cols ----
    {
        const bool isL = (tileX0 == 0);
        const bool isR = (tileX0 == IMG_W - TX);
        if (isL | isR) {
            if (tid < 2 * LH) {
                int r = tid >> 1, k = tid & 1;
                int gy = reflect_idx(tileY0 - HALO + r, IMG_H);
                const float* srow = src + gy * IMG_W;
                if (isL) tile[r * LSTRIDE + 2 + k] = srow[2 - k];        // gx -2,-1 -> 2,1
                else     tile[r * LSTRIDE + 68 + k] = srow[510 - k];     // gx 512,513 -> 510,509
            }
            __syncthreads();
        }
    }
#else
    // fallback: float2-vectorized manual staging
    for (int u = tid; u < LH * (LW / 2); u += 256) {
        int r = u / (LW / 2);
        int c = (u - r * (LW / 2)) * 2;
        int gy = reflect_idx(tileY0 - HALO + r, IMG_H);
        const float* srow = src + gy * IMG_W;
        int gx0 = tileX0 - 4 + c;
        float2 v;
        if (gx0 >= 0 && gx0 + 1 < IMG_W) {
            v = *reinterpret_cast<const float2*>(&srow[gx0]);
        } else {
            v.x = srow[reflect_idx(gx0, IMG_W)];
            v.y = srow[reflect_idx(gx0 + 1, IMG_W)];
        }
        *reinterpret_cast<float2*>(&tile[r * LSTRIDE + c]) = v;
    }
    __syncthreads();
#endif

    const int txg = tid & 7;       // thread x-group: 0..7
    const int ty  = tid >> 3;      // thread row:     0..31
    const int lxw = txg * PXT;     // first word of this thread's 4-quad read window

    const float RC = -72.13475204444817f;        // -1/(2*0.1^2) * log2(e)
    // L[r2] = -r2 * log2(e)/8 = r2 * L1
    const float L1 = -0.18033688011112043f;
    const float L4 = -0.7213475204444817f;
    const v2f RCv = {RC, RC};

    // software-exp2 constants: 2^f ~= 1 + f*(c1 + f*(c2 + f*c3)), f in [-0.5, 0.5]
    const v2f ONEv = {1.0f, 1.0f};
    const v2f XC1v = {0.6931471805599453f,  0.6931471805599453f};   // ln2
    const v2f XC2v = {0.2402265069591007f,  0.2402265069591007f};   // ln2^2/2
    const v2f XC3v = {0.05550410866482158f, 0.05550410866482158f};  // ln2^3/6

    // center row (dy=2): pixels are words +4..+11 = Q1,Q2
    v4f Q20, Q21, Q22, Q23;
    LDROW(2, Q20, Q21, Q22, Q23);
    const v2f cA = {Q21[0], Q21[1]};
    const v2f cB = {Q21[2], Q21[3]};
    const v2f cC = {Q22[0], Q22[1]};
    const v2f cD = {Q22[2], Q22[3]};

    // per-pixel exponent-poly coefficients: arg = RC*n^2 + B*n + (C0 + L[r2])
    const v2f BA = cA * (-2.0f * RC);
    const v2f BB = cB * (-2.0f * RC);
    const v2f BC = cC * (-2.0f * RC);
    const v2f BD = cD * (-2.0f * RC);
    v2f C0A = (cA * cA) * RC;
    v2f C0B = (cB * cB) * RC;
    v2f C0C = (cC * cC) * RC;
    v2f C0D = (cD * cD) * RC;
    const v2f C1A = C0A + L1, C1B = C0B + L1, C1C = C0C + L1, C1D = C0D + L1;
    const v2f C4A = C0A + L4, C4B = C0B + L4, C4C = C0C + L4, C4D = C0D + L4;

    // center tap folded in: weight exactly 1
    v2f wsA = {1.0f, 1.0f}, wsB = {1.0f, 1.0f}, wsC = {1.0f, 1.0f}, wsD = {1.0f, 1.0f};
    v2f accA = cA, accB = cB, accC = cC, accD = cD;

    // dy = 2 first (row already loaded): r2 = {4,1,-,1,4}
    DOROW(Q20, Q21, Q22, Q23,
          C4A, C4B, C4C, C4D, C1A, C1B, C1C, C1D, C1A, C1B, C1C, C1D, true);

    // dy = 1,3 need C5 = C4+L1, C2 = C1+L1  (L5 = L4+L1, L2 = 2*L1)
    const v2f C5A = C4A + L1, C5B = C4B + L1, C5C = C4C + L1, C5D = C4D + L1;
    const v2f C2A = C1A + L1, C2B = C1B + L1, C2C = C1C + L1, C2D = C1D + L1;
    {   // dy = 1: r2 = {5,2,1,2,5}
        v4f Q0, Q1, Q2, Q3;
        LDROW(1, Q0, Q1, Q2, Q3);
        DOROW(Q0, Q1, Q2, Q3,
              C5A, C5B, C5C, C5D, C2A, C2B, C2C, C2D, C1A, C1B, C1C, C1D, false);
    }
    {   // dy = 3: r2 = {5,2,1,2,5}
        v4f Q0, Q1, Q2, Q3;
        LDROW(3, Q0, Q1, Q2, Q3);
        DOROW(Q0, Q1, Q2, Q3,
              C5A, C5B, C5C, C5D, C2A, C2B, C2C, C2D, C1A, C1B, C1C, C1D, false);
    }
    // C1, C2 dead. dy = 0,4 need C8 = C4+L4  (L8 = 2*L4)
    const v2f C8A = C4A + L4, C8B = C4B + L4, C8C = C4C + L4, C8D = C4D + L4;
    {   // dy = 0: r2 = {8,5,4,5,8}
        v4f Q0, Q1, Q2, Q3;
        LDROW(0, Q0, Q1, Q2, Q3);
        DOROW(Q0, Q1, Q2, Q3,
              C8A, C8B, C8C, C8D, C5A, C5B, C5C, C5D, C4A, C4B, C4C, C4D, false);
    }
    {   // dy = 4: r2 = {8,5,4,5,8}
        v4f Q0, Q1, Q2, Q3;
        LDROW(4, Q0, Q1, Q2, Q3);
        DOROW(Q0, Q1, Q2, Q3,
              C8A, C8B, C8C, C8D, C5A, C5B, C5C, C5D, C4A, C4B, C4C, C4D, false);
    }

    const int ox = tileX0 + lxw;
    const int oy = tileY0 + ty;
    float* drow = &dst[oy * IMG_W + ox];
    float4 o0, o1;
    o0.x = accA.x * FAST_RCP(wsA.x);   // ws >= 1 (center tap), clip(1e-10) is dead
    o0.y = accA.y * FAST_RCP(wsA.y);
    o0.z = accB.x * FAST_RCP(wsB.x);
    o0.w = accB.y * FAST_RCP(wsB.y);
    o1.x = accC.x * FAST_RCP(wsC.x);
    o1.y = accC.y * FAST_RCP(wsC.y);
    o1.z = accD.x * FAST_RCP(wsD.x);
    o1.w = accD.y * FAST_RCP(wsD.y);
    *reinterpret_cast<float4*>(drow) = o0;
    *reinterpret_cast<float4*>(drow + 4) = o1;
}

extern "C" void kernel_launch(void* const* d_in, const int* in_sizes, int n_in,
                              void* d_out, int out_size, void* d_ws, size_t ws_size,
                              hipStream_t stream) {
    const float* x = (const float*)d_in[0];
    // d_in[1] (spatial 5x5) is analytically exp(-(dx^2+dy^2)/8); folded into constants.
    float* out = (float*)d_out;

    const int n_img = out_size / (IMG_H * IMG_W);   // B*C = 24
    dim3 grid(IMG_W / TX, IMG_H / TY, n_img);       // (8, 16, 24)
    dim3 block(256);
    hipLaunchKernelGGL(bilateral_kernel, grid, block, 0, stream, x, out);
}

// Round 10
// 99.341 us; speedup vs baseline: 1.0600x; 1.0600x over previous
//
#include <hip/hip_runtime.h>
#include <stdint.h>

// Bilateral filter denoiser: K=5, sigma_s=2.0, sigma_r=0.1, B=8,C=3,H=512,W=512, fp32.
// weight(dy,dx) = exp(-(n-c)^2/(2*0.1^2)) * exp(-(dx^2+dy^2)/8)
//              = exp2( RC*(n-c)^2 + L[r2] ),  r2 = (dy-2)^2+(dx-2)^2, L[r2] = -r2*log2(e)/8
// arg computed as fma(fma(RC,n,B), n, C0L); C-sets chained just-in-time (row order
// 2,1,3,0,4) so peak C-live is 4 sets.
//
// ROUND 10: HYBRID exp2 -- halves A,B use hardware v_exp_f32 (trans pipe), halves C,D
// use the software rint/ldexp path (VALU pipe). Evidence: r5 (all-HW) = ~34us dispatch;
// r9 (all-SW, correct) = ~+7us REGRESSION equal to its added VALU issue cost. So trans
// mostly co-issues with other waves' VALU work, and VALU instr count is on the critical
// path -> balance the two pipes instead of loading either one fully:
//   all-HW: trans ~96*2*16 cyc dominated | hybrid: trans 96*16 ~= VALU 920+96*10.
// SW path (r9-proven): r=rintf(t); f=t-r in [-.5,.5]; p=deg-3 Taylor (3 v_pk_fma);
// dst=ldexp(p,(int)r) -- exact scaling, no bit tricks, fast-math-robust.
//
// 8 px/thread (four float2 halves -> v_pk_* packed fp32), 64x32 tile, 256 threads.
// ALL compute is MACROS: the inliner OUTLINES large [&]-capture lambdas at 24 call
// sites (capture struct in scratch, +200 MB HBM traffic -- rounds 3-4).
// Single-tile structure (r7 tile-pair pipeline was neutral-negative).
// __launch_bounds__(256,3) (r5's best variant; gives regalloc room for poly consts).
//
// Staging: async global->LDS via __builtin_amdgcn_global_load_lds width=16.
// Tile rows are 72 words (288B = 18x16B units) covering gx in [tileX0-4, tileX0+68):
//   - rows 16B-aligned, LDS written linearly (wave-uniform base + lane*16) as HW needs
//   - per-lane global address handles y-reflect; x CLAMPED to [0,508] (garbage cols are
//     outside the compute window except 2 cols on x-border blocks, fixed up scalar)
//   - 648 units = 3 gload_lds instrs/wave (64 + 64 + 34 active lanes)
// Compute window per thread = 16 words [txg*8, txg*8+16): four aligned ds_read_b128;
// pixels are words +4..+11 (Q1,Q2), taps use words +2..+13.
// Center tap: weight == 1 exactly -> ws init 1, acc init c; ws>=1 so no clip, rcp ok.

#define KK 5
#define HALO 2
#define TX 64          // tile width (pixels)
#define TY 32          // tile height
#define PXT 8          // pixels per thread along x
#define LW 72          // staged words per row: [tileX0-4, tileX0+68)
#define LH (TY + 2*HALO)   // 36 rows
#define LSTRIDE 72         // 288B rows, 16B-aligned
#define UNITS_PER_ROW 18   // 72 words / 4
#define IMG_H 512
#define IMG_W 512

typedef float v2f __attribute__((ext_vector_type(2)));
typedef float v4f __attribute__((ext_vector_type(4)));

#if defined(__has_builtin)
#if __has_builtin(__builtin_amdgcn_exp2f)
#define FAST_EXP2(x) __builtin_amdgcn_exp2f(x)
#else
#define FAST_EXP2(x) exp2f(x)
#endif
#if __has_builtin(__builtin_amdgcn_rcpf)
#define FAST_RCP(x) __builtin_amdgcn_rcpf(x)
#else
#define FAST_RCP(x) (1.0f / (x))
#endif
#if __has_builtin(__builtin_amdgcn_ldexpf)
#define LDEXPF(p, i) __builtin_amdgcn_ldexpf((p), (i))
#else
// i in [-74,0] -> biased exp in [53,127]: plain exponent build, no wrap cases.
#define LDEXPF(p, i) ((p) * __builtin_bit_cast(float, (uint32_t)(((i) + 127) << 23)))
#endif
#if __has_builtin(__builtin_amdgcn_global_load_lds)
#define HAVE_GLOAD_LDS 1
#endif
#else
#define FAST_EXP2(x) exp2f(x)
#define FAST_RCP(x) (1.0f / (x))
#define LDEXPF(p, i) ldexpf((p), (i))
#endif

__device__ __forceinline__ int reflect_idx(int i, int n) {
    i = (i < 0) ? -i : i;
    i = (i >= n) ? (2 * n - 2 - i) : i;
    return i;
}

#ifdef HAVE_GLOAD_LDS
__device__ __forceinline__ void async_copy16(const float* g, float* l) {
    // generic->AS(1) cast for global src; LDS ptr via 32-bit truncation (flat LDS
    // addresses are aperture|offset with 4GB-aligned aperture -> low 32 bits = offset).
    auto gp = (const __attribute__((address_space(1))) void*)g;
    auto lp = (__attribute__((address_space(3))) void*)(uint32_t)(uintptr_t)l;
    __builtin_amdgcn_global_load_lds(gp, lp, 16, 0, 0);
}
#endif

// ---- macro compute core (no function boundaries) ----
#define PKFMA(a, b, c) __builtin_elementwise_fma((a), (b), (c))

// hardware exp2 on v2f (trans pipe)
#define EXP2HW(dst, t) {                                                        \
    (dst).x = FAST_EXP2((t).x);                                                 \
    (dst).y = FAST_EXP2((t).y);                                                 \
}

// software exp2 on v2f (VALU pipe), t in [-74, 0]: r9-proven robust path.
#define EXP2SW(dst, t) {                                                        \
    float rx_ = __builtin_rintf((t).x);                                         \
    float ry_ = __builtin_rintf((t).y);                                         \
    v2f rv_ = {rx_, ry_};                                                       \
    v2f f_ = (t) - rv_;                                                         \
    v2f p_ = PKFMA(PKFMA(PKFMA(XC3v, f_, XC2v), f_, XC1v), f_, ONEv);           \
    (dst).x = LDEXPF(p_.x, (int)rx_);                                           \
    (dst).y = LDEXPF(p_.y, (int)ry_);                                           \
}

// hybrid: A,B -> trans pipe; C,D -> VALU pipe (pipe balancing, see header)
#define TAP(nA, nB, nC, nD, CA, CB, CC, CD) {                                   \
    v2f tA_ = PKFMA(PKFMA(RCv, (nA), BA), (nA), (CA));                          \
    v2f tB_ = PKFMA(PKFMA(RCv, (nB), BB), (nB), (CB));                          \
    v2f tC_ = PKFMA(PKFMA(RCv, (nC), BC), (nC), (CC));                          \
    v2f tD_ = PKFMA(PKFMA(RCv, (nD), BD), (nD), (CD));                          \
    v2f eA_, eB_, eC_, eD_;                                                     \
    EXP2HW(eA_, tA_);                                                           \
    EXP2HW(eB_, tB_);                                                           \
    EXP2SW(eC_, tC_);                                                           \
    EXP2SW(eD_, tD_);                                                           \
    wsA += eA_; wsB += eB_; wsC += eC_; wsD += eD_;                             \
    accA = PKFMA(eA_, (nA), accA);                                              \
    accB = PKFMA(eB_, (nB), accB);                                              \
    accC = PKFMA(eC_, (nC), accC);                                              \
    accD = PKFMA(eD_, (nD), accD);                                              \
}

// window words w0..w15 (quads Qa..Qd), taps use w2..w13.
// even pairs Ek=(w2k,w2k+1) k=1..6; odd pairs Ok=(w2k+1,w2k+2) k=1..5.
//  dx0:(E1..E4)  dx1:(O1..O4)  dx2:(E2..E5)  dx3:(O2..O5)  dx4:(E3..E6)
#define DOROW(Qa, Qb, Qc, Qd, CaA,CaB,CaC,CaD, CbA,CbB,CbC,CbD, CcA,CcB,CcC,CcD, CENTER) { \
    v2f E1_ = {Qa[2], Qa[3]};                                                   \
    v2f E2_ = {Qb[0], Qb[1]};                                                   \
    v2f E3_ = {Qb[2], Qb[3]};                                                   \
    v2f E4_ = {Qc[0], Qc[1]};                                                   \
    v2f E5_ = {Qc[2], Qc[3]};                                                   \
    v2f E6_ = {Qd[0], Qd[1]};                                                   \
    v2f O1_ = {Qa[3], Qb[0]};                                                   \
    v2f O2_ = {Qb[1], Qb[2]};                                                   \
    v2f O3_ = {Qb[3], Qc[0]};                                                   \
    v2f O4_ = {Qc[1], Qc[2]};                                                   \
    v2f O5_ = {Qc[3], Qd[0]};                                                   \
    TAP(E1_, E2_, E3_, E4_, CaA, CaB, CaC, CaD);          /* dx = 0 */          \
    TAP(O1_, O2_, O3_, O4_, CbA, CbB, CbC, CbD);          /* dx = 1 */          \
    if (!(CENTER)) TAP(E2_, E3_, E4_, E5_, CcA, CcB, CcC, CcD); /* dx = 2 */    \
    TAP(O2_, O3_, O4_, O5_, CbA, CbB, CbC, CbD);          /* dx = 3 */          \
    TAP(E3_, E4_, E5_, E6_, CaA, CaB, CaC, CaD);          /* dx = 4 */          \
}

#define LDROW(dy, Qa, Qb, Qc, Qd) {                                             \
    const v4f* p_ = reinterpret_cast<const v4f*>(&tile[(ty + (dy)) * LSTRIDE + lxw]); \
    Qa = p_[0]; Qb = p_[1]; Qc = p_[2]; Qd = p_[3];                             \
}

__global__ __launch_bounds__(256, 3)
void bilateral_kernel(const float* __restrict__ x, float* __restrict__ out) {
    __shared__ alignas(16) float tile[LH * LSTRIDE];

    const int tid = threadIdx.x;
    const int tileX0 = blockIdx.x * TX;
    const int tileY0 = blockIdx.y * TY;
    const int img = blockIdx.z;
    const float* __restrict__ src = x + (size_t)img * (IMG_H * IMG_W);
    float* __restrict__ dst = out + (size_t)img * (IMG_H * IMG_W);

#ifdef HAVE_GLOAD_LDS
    // ---- async stage: 648 16B units over 4 waves (162 each = 64 + 64 + 34) ----
    {
        const int wv = tid >> 6;
        const int ln = tid & 63;
        const int u0 = wv * 162;
        #pragma unroll
        for (int k = 0; k < 3; k++) {
            if (k < 2 || ln < 34) {
                int u = u0 + k * 64 + ln;
                int r = u / UNITS_PER_ROW;
                int c = u - r * UNITS_PER_ROW;
                int gy = reflect_idx(tileY0 - HALO + r, IMG_H);
                int gxw = tileX0 - 4 + c * 4;
                gxw = max(gxw, 0); gxw = min(gxw, IMG_W - 4);
                async_copy16(src + gy * IMG_W + gxw, &tile[(u0 + k * 64) * 4]);
            }
        }
    }
    __syncthreads();   // drains vmcnt -> gload_lds data visible

    // ---- x-border fixup: clamped loads put wrong values in 2 needed halo cols ----
    {
        const bool isL = (tileX0 == 0);
        const bool isR = (tileX0 == IMG_W - TX);
        if (isL | isR) {
            if (tid < 2 * LH) {
                int r = tid >> 1, k = tid & 1;
                int gy = reflect_idx(tileY0 - HALO + r, IMG_H);
                const float* srow = src + gy * IMG_W;
                if (isL) tile[r * LSTRIDE + 2 + k] = srow[2 - k];        // gx -2,-1 -> 2,1
                else     tile[r * LSTRIDE + 68 + k] = srow[510 - k];     // gx 512,513 -> 510,509
            }
            __syncthreads();
        }
    }
#else
    // fallback: float2-vectorized manual staging
    for (int u = tid; u < LH * (LW / 2); u += 256) {
        int r = u / (LW / 2);
        int c = (u - r * (LW / 2)) * 2;
        int gy = reflect_idx(tileY0 - HALO + r, IMG_H);
        const float* srow = src + gy * IMG_W;
        int gx0 = tileX0 - 4 + c;
        float2 v;
        if (gx0 >= 0 && gx0 + 1 < IMG_W) {
            v = *reinterpret_cast<const float2*>(&srow[gx0]);
        } else {
            v.x = srow[reflect_idx(gx0, IMG_W)];
            v.y = srow[reflect_idx(gx0 + 1, IMG_W)];
        }
        *reinterpret_cast<float2*>(&tile[r * LSTRIDE + c]) = v;
    }
    __syncthreads();
#endif

    const int txg = tid & 7;       // thread x-group: 0..7
    const int ty  = tid >> 3;      // thread row:     0..31
    const int lxw = txg * PXT;     // first word of this thread's 4-quad read window

    const float RC = -72.13475204444817f;        // -1/(2*0.1^2) * log2(e)
    // L[r2] = -r2 * log2(e)/8 = r2 * L1
    const float L1 = -0.18033688011112043f;
    const float L4 = -0.7213475204444817f;
    const v2f RCv = {RC, RC};

    // software-exp2 constants: 2^f ~= 1 + f*(c1 + f*(c2 + f*c3)), f in [-0.5, 0.5]
    const v2f ONEv = {1.0f, 1.0f};
    const v2f XC1v = {0.6931471805599453f,  0.6931471805599453f};   // ln2
    const v2f XC2v = {0.2402265069591007f,  0.2402265069591007f};   // ln2^2/2
    const v2f XC3v = {0.05550410866482158f, 0.05550410866482158f};  // ln2^3/6

    // center row (dy=2): pixels are words +4..+11 = Q1,Q2
    v4f Q20, Q21, Q22, Q23;
    LDROW(2, Q20, Q21, Q22, Q23);
    const v2f cA = {Q21[0], Q21[1]};
    const v2f cB = {Q21[2], Q21[3]};
    const v2f cC = {Q22[0], Q22[1]};
    const v2f cD = {Q22[2], Q22[3]};

    // per-pixel exponent-poly coefficients: arg = RC*n^2 + B*n + (C0 + L[r2])
    const v2f BA = cA * (-2.0f * RC);
    const v2f BB = cB * (-2.0f * RC);
    const v2f BC = cC * (-2.0f * RC);
    const v2f BD = cD * (-2.0f * RC);
    v2f C0A = (cA * cA) * RC;
    v2f C0B = (cB * cB) * RC;
    v2f C0C = (cC * cC) * RC;
    v2f C0D = (cD * cD) * RC;
    const v2f C1A = C0A + L1, C1B = C0B + L1, C1C = C0C + L1, C1D = C0D + L1;
    const v2f C4A = C0A + L4, C4B = C0B + L4, C4C = C0C + L4, C4D = C0D + L4;

    // center tap folded in: weight exactly 1
    v2f wsA = {1.0f, 1.0f}, wsB = {1.0f, 1.0f}, wsC = {1.0f, 1.0f}, wsD = {1.0f, 1.0f};
    v2f accA = cA, accB = cB, accC = cC, accD = cD;

    // dy = 2 first (row already loaded): r2 = {4,1,-,1,4}
    DOROW(Q20, Q21, Q22, Q23,
          C4A, C4B, C4C, C4D, C1A, C1B, C1C, C1D, C1A, C1B, C1C, C1D, true);

    // dy = 1,3 need C5 = C4+L1, C2 = C1+L1  (L5 = L4+L1, L2 = 2*L1)
    const v2f C5A = C4A + L1, C5B = C4B + L1, C5C = C4C + L1, C5D = C4D + L1;
    const v2f C2A = C1A + L1, C2B = C1B + L1, C2C = C1C + L1, C2D = C1D + L1;
    {   // dy = 1: r2 = {5,2,1,2,5}
        v4f Q0, Q1, Q2, Q3;
        LDROW(1, Q0, Q1, Q2, Q3);
        DOROW(Q0, Q1, Q2, Q3,
              C5A, C5B, C5C, C5D, C2A, C2B, C2C, C2D, C1A, C1B, C1C, C1D, false);
    }
    {   // dy = 3: r2 = {5,2,1,2,5}
        v4f Q0, Q1, Q2, Q3;
        LDROW(3, Q0, Q1, Q2, Q3);
        DOROW(Q0, Q1, Q2, Q3,
              C5A, C5B, C5C, C5D, C2A, C2B, C2C, C2D, C1A, C1B, C1C, C1D, false);
    }
    // C1, C2 dead. dy = 0,4 need C8 = C4+L4  (L8 = 2*L4)
    const v2f C8A = C4A + L4, C8B = C4B + L4, C8C = C4C + L4, C8D = C4D + L4;
    {   // dy = 0: r2 = {8,5,4,5,8}
        v4f Q0, Q1, Q2, Q3;
        LDROW(0, Q0, Q1, Q2, Q3);
        DOROW(Q0, Q1, Q2, Q3,
              C8A, C8B, C8C, C8D, C5A, C5B, C5C, C5D, C4A, C4B, C4C, C4D, false);
    }
    {   // dy = 4: r2 = {8,5,4,5,8}
        v4f Q0, Q1, Q2, Q3;
        LDROW(4, Q0, Q1, Q2, Q3);
        DOROW(Q0, Q1, Q2, Q3,
              C8A, C8B, C8C, C8D, C5A, C5B, C5C, C5D, C4A, C4B, C4C, C4D, false);
    }

    const int ox = tileX0 + lxw;
    const int oy = tileY0 + ty;
    float* drow = &dst[oy * IMG_W + ox];
    float4 o0, o1;
    o0.x = accA.x * FAST_RCP(wsA.x);   // ws >= 1 (center tap), clip(1e-10) is dead
    o0.y = accA.y * FAST_RCP(wsA.y);
    o0.z = accB.x * FAST_RCP(wsB.x);
    o0.w = accB.y * FAST_RCP(wsB.y);
    o1.x = accC.x * FAST_RCP(wsC.x);
    o1.y = accC.y * FAST_RCP(wsC.y);
    o1.z = accD.x * FAST_RCP(wsD.x);
    o1.w = accD.y * FAST_RCP(wsD.y);
    *reinterpret_cast<float4*>(drow) = o0;
    *reinterpret_cast<float4*>(drow + 4) = o1;
}

extern "C" void kernel_launch(void* const* d_in, const int* in_sizes, int n_in,
                              void* d_out, int out_size, void* d_ws, size_t ws_size,
                              hipStream_t stream) {
    const float* x = (const float*)d_in[0];
    // d_in[1] (spatial 5x5) is analytically exp(-(dx^2+dy^2)/8); folded into constants.
    float* out = (float*)d_out;

    const int n_img = out_size / (IMG_H * IMG_W);   // B*C = 24
    dim3 grid(IMG_W / TX, IMG_H / TY, n_img);       // (8, 16, 24)
    dim3 block(256);
    hipLaunchKernelGGL(bilateral_kernel, grid, block, 0, stream, x, out);
}

// Round 11
// 93.134 us; speedup vs baseline: 1.1306x; 1.0666x over previous
//
#include <hip/hip_runtime.h>
#include <stdint.h>

// Bilateral filter denoiser: K=5, sigma_s=2.0, sigma_r=0.1, B=8,C=3,H=512,W=512, fp32.
// weight(dy,dx) = exp(-(n-c)^2/(2*0.1^2)) * exp(-(dx^2+dy^2)/8)
//              = exp2( RC*(n-c)^2 + L[r2] ),  r2 = (dy-2)^2+(dx-2)^2, L[r2] = -r2*log2(e)/8
// arg = fma(fma(RC,n,B), n, C0L); C-sets chained just-in-time (row order 2,1,3,0,4).
// exp2 is ALL-HARDWARE v_exp_f32: r9 (all-SW) and r10 (hybrid) both regressed --
// trans co-issues nearly free; added VALU emulation lands at full price (r5=92.3 <
// r10=99.3 < r9=105.3 monotone in SW share).
//
// ROUND 11: LDS bank balance + minimal reads. Old LSTRIDE=72 words: wave ds_read_b128
// addrs (72*ty + 8*txg) mod 32 = 8*((ty+txg)%4) -> 64 lanes on 4 four-bank groups,
// 16 words/bank (2x the balanced load) = the measured 2.46M SQ_LDS_BANK_CONFLICT.
// New LSTRIDE=LW=68 (halo offset -2): 68 mod 32 = 4 -> lanes spread over ALL 32 banks,
// 8 words/bank (b128 minimum, zero structural conflict). Window = 12 words = 3 quads
// exactly (was 4 quads with 4 wasted words): -25% LDS instructions.
// Cost: border fixup widens to 4 cols/side (clamp misaligns edge unit by 2 words);
// 144 threads, only on the 2 border block-columns.
//
// 8 px/thread (four float2 halves -> v_pk_* packed fp32), 64x32 tile, 256 threads.
// ALL compute is MACROS: the inliner OUTLINES large [&]-capture lambdas at 24 call
// sites (capture struct in scratch, +200 MB HBM traffic -- rounds 3-4).
// Single-tile structure (r7 tile-pair pipeline negative); __launch_bounds__(256,3).
//
// Staging: async global->LDS via __builtin_amdgcn_global_load_lds width=16.
// Rows of 68 words (272B = 17x16B units) covering gx in [tileX0-2, tileX0+66):
//   - rows 16B-aligned, LDS written linearly (wave-uniform base + lane*16) as HW needs
//   - per-lane global address handles y-reflect; x CLAMPED to [0,508]; border blocks
//     fix 4 halo cols per side scalar after the barrier
//   - 612 units = 3 gload_lds instrs/wave (64 + 64 + 25 active lanes)
// Compute window per thread = 12 words [txg*8, txg*8+12): THREE aligned ds_read_b128;
// pixels are words +2..+9 (P1..P4), taps use all 12.
// Center tap: weight == 1 exactly -> ws init 1, acc init c; ws>=1 so no clip, rcp ok.

#define KK 5
#define HALO 2
#define TX 64          // tile width (pixels)
#define TY 32          // tile height
#define PXT 8          // pixels per thread along x
#define LW 68          // staged words per row: [tileX0-2, tileX0+66)
#define LH (TY + 2*HALO)   // 36 rows
#define LSTRIDE 68         // 272B rows, 16B-aligned, 32-bank-balanced (68%32==4)
#define UNITS_PER_ROW 17   // 68 words / 4
#define IMG_H 512
#define IMG_W 512

typedef float v2f __attribute__((ext_vector_type(2)));
typedef float v4f __attribute__((ext_vector_type(4)));

#if defined(__has_builtin)
#if __has_builtin(__builtin_amdgcn_exp2f)
#define FAST_EXP2(x) __builtin_amdgcn_exp2f(x)
#else
#define FAST_EXP2(x) exp2f(x)
#endif
#if __has_builtin(__builtin_amdgcn_rcpf)
#define FAST_RCP(x) __builtin_amdgcn_rcpf(x)
#else
#define FAST_RCP(x) (1.0f / (x))
#endif
#if __has_builtin(__builtin_amdgcn_global_load_lds)
#define HAVE_GLOAD_LDS 1
#endif
#else
#define FAST_EXP2(x) exp2f(x)
#define FAST_RCP(x) (1.0f / (x))
#endif

__device__ __forceinline__ int reflect_idx(int i, int n) {
    i = (i < 0) ? -i : i;
    i = (i >= n) ? (2 * n - 2 - i) : i;
    return i;
}

#ifdef HAVE_GLOAD_LDS
__device__ __forceinline__ void async_copy16(const float* g, float* l) {
    // generic->AS(1) cast for global src; LDS ptr via 32-bit truncation (flat LDS
    // addresses are aperture|offset with 4GB-aligned aperture -> low 32 bits = offset).
    auto gp = (const __attribute__((address_space(1))) void*)g;
    auto lp = (__attribute__((address_space(3))) void*)(uint32_t)(uintptr_t)l;
    __builtin_amdgcn_global_load_lds(gp, lp, 16, 0, 0);
}
#endif

// ---- macro compute core (no function boundaries) ----
#define PKFMA(a, b, c) __builtin_elementwise_fma((a), (b), (c))

#define TAP(nA, nB, nC, nD, CA, CB, CC, CD) {                                   \
    v2f tA_ = PKFMA(PKFMA(RCv, (nA), BA), (nA), (CA));                          \
    v2f tB_ = PKFMA(PKFMA(RCv, (nB), BB), (nB), (CB));                          \
    v2f tC_ = PKFMA(PKFMA(RCv, (nC), BC), (nC), (CC));                          \
    v2f tD_ = PKFMA(PKFMA(RCv, (nD), BD), (nD), (CD));                          \
    v2f eA_, eB_, eC_, eD_;                                                     \
    eA_.x = FAST_EXP2(tA_.x); eA_.y = FAST_EXP2(tA_.y);                         \
    eB_.x = FAST_EXP2(tB_.x); eB_.y = FAST_EXP2(tB_.y);                         \
    eC_.x = FAST_EXP2(tC_.x); eC_.y = FAST_EXP2(tC_.y);                         \
    eD_.x = FAST_EXP2(tD_.x); eD_.y = FAST_EXP2(tD_.y);                         \
    wsA += eA_; wsB += eB_; wsC += eC_; wsD += eD_;                             \
    accA = PKFMA(eA_, (nA), accA);                                              \
    accB = PKFMA(eB_, (nB), accB);                                              \
    accC = PKFMA(eC_, (nC), accC);                                              \
    accD = PKFMA(eD_, (nD), accD);                                              \
}

// window words w0..w11 (quads Qa,Qb,Qc); pixels = w2..w9.
// even pairs Pk=(w2k,w2k+1) k=0..5; odd pairs Rk=(w2k+1,w2k+2) k=0..4.
//  dx0:(P0..P3)  dx1:(R0..R3)  dx2:(P1..P4)  dx3:(R1..R4)  dx4:(P2..P5)
#define DOROW(Qa, Qb, Qc, CaA,CaB,CaC,CaD, CbA,CbB,CbC,CbD, CcA,CcB,CcC,CcD, CENTER) { \
    v2f P0_ = {Qa[0], Qa[1]};                                                   \
    v2f P1_ = {Qa[2], Qa[3]};                                                   \
    v2f P2_ = {Qb[0], Qb[1]};                                                   \
    v2f P3_ = {Qb[2], Qb[3]};                                                   \
    v2f P4_ = {Qc[0], Qc[1]};                                                   \
    v2f P5_ = {Qc[2], Qc[3]};                                                   \
    v2f R0_ = {Qa[1], Qa[2]};                                                   \
    v2f R1_ = {Qa[3], Qb[0]};                                                   \
    v2f R2_ = {Qb[1], Qb[2]};                                                   \
    v2f R3_ = {Qb[3], Qc[0]};                                                   \
    v2f R4_ = {Qc[1], Qc[2]};                                                   \
    TAP(P0_, P1_, P2_, P3_, CaA, CaB, CaC, CaD);          /* dx = 0 */          \
    TAP(R0_, R1_, R2_, R3_, CbA, CbB, CbC, CbD);          /* dx = 1 */          \
    if (!(CENTER)) TAP(P1_, P2_, P3_, P4_, CcA, CcB, CcC, CcD); /* dx = 2 */    \
    TAP(R1_, R2_, R3_, R4_, CbA, CbB, CbC, CbD);          /* dx = 3 */          \
    TAP(P2_, P3_, P4_, P5_, CaA, CaB, CaC, CaD);          /* dx = 4 */          \
}

#define LDROW(dy, Qa, Qb, Qc) {                                                 \
    const v4f* p_ = reinterpret_cast<const v4f*>(&tile[(ty + (dy)) * LSTRIDE + lxw]); \
    Qa = p_[0]; Qb = p_[1]; Qc = p_[2];                                         \
}

__global__ __launch_bounds__(256, 3)
void bilateral_kernel(const float* __restrict__ x, float* __restrict__ out) {
    __shared__ alignas(16) float tile[LH * LSTRIDE];

    const int tid = threadIdx.x;
    const int tileX0 = blockIdx.x * TX;
    const int tileY0 = blockIdx.y * TY;
    const int img = blockIdx.z;
    const float* __restrict__ src = x + (size_t)img * (IMG_H * IMG_W);
    float* __restrict__ dst = out + (size_t)img * (IMG_H * IMG_W);

#ifdef HAVE_GLOAD_LDS
    // ---- async stage: 612 16B units over 4 waves (153 each = 64 + 64 + 25) ----
    {
        const int wv = tid >> 6;
        const int ln = tid & 63;
        const int u0 = wv * 153;
        #pragma unroll
        for (int k = 0; k < 3; k++) {
            if (k < 2 || ln < 25) {
                int u = u0 + k * 64 + ln;
                int r = u / UNITS_PER_ROW;
                int c = u - r * UNITS_PER_ROW;
                int gy = reflect_idx(tileY0 - HALO + r, IMG_H);
                int gxw = tileX0 - 2 + c * 4;
                gxw = max(gxw, 0); gxw = min(gxw, IMG_W - 4);
                async_copy16(src + gy * IMG_W + gxw, &tile[(u0 + k * 64) * 4]);
            }
        }
    }
    __syncthreads();   // drains vmcnt -> gload_lds data visible

    // ---- x-border fixup: clamped edge units hold shifted values in 4 halo cols ----
    {
        const bool isL = (tileX0 == 0);
        const bool isR = (tileX0 == IMG_W - TX);
        if (isL | isR) {
            if (tid < 4 * LH) {
                int r = tid >> 2, k = tid & 3;
                int gy = reflect_idx(tileY0 - HALO + r, IMG_H);
                const float* srow = src + gy * IMG_W;
                if (isL) {
                    // cols 0..3 <- gx -2..1 reflected: srow[2],srow[1],srow[0],srow[1]
                    tile[r * LSTRIDE + k] = srow[reflect_idx(k - 2, IMG_W)];
                } else {
                    // cols 64..67 <- gx 510..513 refl: srow[510],srow[511],srow[510],srow[509]
                    tile[r * LSTRIDE + 64 + k] = srow[reflect_idx(510 + k, IMG_W)];
                }
            }
            __syncthreads();
        }
    }
#else
    // fallback: float2-vectorized manual staging
    for (int u = tid; u < LH * (LW / 2); u += 256) {
        int r = u / (LW / 2);
        int c = (u - r * (LW / 2)) * 2;
        int gy = reflect_idx(tileY0 - HALO + r, IMG_H);
        const float* srow = src + gy * IMG_W;
        int gx0 = tileX0 - 2 + c;
        float2 v;
        if (gx0 >= 0 && gx0 + 1 < IMG_W) {
            v = *reinterpret_cast<const float2*>(&srow[gx0]);
        } else {
            v.x = srow[reflect_idx(gx0, IMG_W)];
            v.y = srow[reflect_idx(gx0 + 1, IMG_W)];
        }
        *reinterpret_cast<float2*>(&tile[r * LSTRIDE + c]) = v;
    }
    __syncthreads();
#endif

    const int txg = tid & 7;       // thread x-group: 0..7
    const int ty  = tid >> 3;      // thread row:     0..31
    const int lxw = txg * PXT;     // first word of this thread's 3-quad read window

    const float RC = -72.13475204444817f;        // -1/(2*0.1^2) * log2(e)
    // L[r2] = -r2 * log2(e)/8 = r2 * L1
    const float L1 = -0.18033688011112043f;
    const float L4 = -0.7213475204444817f;
    const v2f RCv = {RC, RC};

    // center row (dy=2): pixels are words +2..+9 = P1..P4
    v4f Q2a, Q2b, Q2c;
    LDROW(2, Q2a, Q2b, Q2c);
    const v2f cA = {Q2a[2], Q2a[3]};
    const v2f cB = {Q2b[0], Q2b[1]};
    const v2f cC = {Q2b[2], Q2b[3]};
    const v2f cD = {Q2c[0], Q2c[1]};

    // per-pixel exponent-poly coefficients: arg = RC*n^2 + B*n + (C0 + L[r2])
    const v2f BA = cA * (-2.0f * RC);
    const v2f BB = cB * (-2.0f * RC);
    const v2f BC = cC * (-2.0f * RC);
    const v2f BD = cD * (-2.0f * RC);
    v2f C0A = (cA * cA) * RC;
    v2f C0B = (cB * cB) * RC;
    v2f C0C = (cC * cC) * RC;
    v2f C0D = (cD * cD) * RC;
    const v2f C1A = C0A + L1, C1B = C0B + L1, C1C = C0C + L1, C1D = C0D + L1;
    const v2f C4A = C0A + L4, C4B = C0B + L4, C4C = C0C + L4, C4D = C0D + L4;

    // center tap folded in: weight exactly 1
    v2f wsA = {1.0f, 1.0f}, wsB = {1.0f, 1.0f}, wsC = {1.0f, 1.0f}, wsD = {1.0f, 1.0f};
    v2f accA = cA, accB = cB, accC = cC, accD = cD;

    // dy = 2 first (row already loaded): r2 = {4,1,-,1,4}
    DOROW(Q2a, Q2b, Q2c,
          C4A, C4B, C4C, C4D, C1A, C1B, C1C, C1D, C1A, C1B, C1C, C1D, true);

    // dy = 1,3 need C5 = C4+L1, C2 = C1+L1  (L5 = L4+L1, L2 = 2*L1)
    const v2f C5A = C4A + L1, C5B = C4B + L1, C5C = C4C + L1, C5D = C4D + L1;
    const v2f C2A = C1A + L1, C2B = C1B + L1, C2C = C1C + L1, C2D = C1D + L1;
    {   // dy = 1: r2 = {5,2,1,2,5}
        v4f Qa, Qb, Qc;
        LDROW(1, Qa, Qb, Qc);
        DOROW(Qa, Qb, Qc,
              C5A, C5B, C5C, C5D, C2A, C2B, C2C, C2D, C1A, C1B, C1C, C1D, false);
    }
    {   // dy = 3: r2 = {5,2,1,2,5}
        v4f Qa, Qb, Qc;
        LDROW(3, Qa, Qb, Qc);
        DOROW(Qa, Qb, Qc,
              C5A, C5B, C5C, C5D, C2A, C2B, C2C, C2D, C1A, C1B, C1C, C1D, false);
    }
    // C1, C2 dead. dy = 0,4 need C8 = C4+L4  (L8 = 2*L4)
    const v2f C8A = C4A + L4, C8B = C4B + L4, C8C = C4C + L4, C8D = C4D + L4;
    {   // dy = 0: r2 = {8,5,4,5,8}
        v4f Qa, Qb, Qc;
        LDROW(0, Qa, Qb, Qc);
        DOROW(Qa, Qb, Qc,
              C8A, C8B, C8C, C8D, C5A, C5B, C5C, C5D, C4A, C4B, C4C, C4D, false);
    }
    {   // dy = 4: r2 = {8,5,4,5,8}
        v4f Qa, Qb, Qc;
        LDROW(4, Qa, Qb, Qc);
        DOROW(Qa, Qb, Qc,
              C8A, C8B, C8C, C8D, C5A, C5B, C5C, C5D, C4A, C4B, C4C, C4D, false);
    }

    const int ox = tileX0 + lxw;
    const int oy = tileY0 + ty;
    float* drow = &dst[oy * IMG_W + ox];
    float4 o0, o1;
    o0.x = accA.x * FAST_RCP(wsA.x);   // ws >= 1 (center tap), clip(1e-10) is dead
    o0.y = accA.y * FAST_RCP(wsA.y);
    o0.z = accB.x * FAST_RCP(wsB.x);
    o0.w = accB.y * FAST_RCP(wsB.y);
    o1.x = accC.x * FAST_RCP(wsC.x);
    o1.y = accC.y * FAST_RCP(wsC.y);
    o1.z = accD.x * FAST_RCP(wsD.x);
    o1.w = accD.y * FAST_RCP(wsD.y);
    *reinterpret_cast<float4*>(drow) = o0;
    *reinterpret_cast<float4*>(drow + 4) = o1;
}

extern "C" void kernel_launch(void* const* d_in, const int* in_sizes, int n_in,
                              void* d_out, int out_size, void* d_ws, size_t ws_size,
                              hipStream_t stream) {
    const float* x = (const float*)d_in[0];
    // d_in[1] (spatial 5x5) is analytically exp(-(dx^2+dy^2)/8); folded into constants.
    float* out = (float*)d_out;

    const int n_img = out_size / (IMG_H * IMG_W);   // B*C = 24
    dim3 grid(IMG_W / TX, IMG_H / TY, n_img);       // (8, 16, 24)
    dim3 block(256);
    hipLaunchKernelGGL(bilateral_kernel, grid, block, 0, stream, x, out);
}